// Round 2
// baseline (41713.565 us; speedup 1.0000x reference)
//
#include <hip/hip_runtime.h>
#include <cstdint>
#include <cstddef>

#define T_STEPS 256
#define BATCH   128
#define VOCAB   256
#define EDIM    512
#define NH      1024
#define GDIM    4096   // 4*NH

__device__ __forceinline__ float sigmoidf_(float x) { return 1.0f / (1.0f + __expf(-x)); }
__device__ __forceinline__ float tanhf_(float x)    { return 1.0f - 2.0f / (__expf(2.0f * x) + 1.0f); }

// ---------------- generic fp32 GEMM: C = A(MxK) @ B(KxN) (+bias) ----------------
// 128x128 tile, BK=16, 256 threads, 8x8 per-thread microtile.
// Requires M%128==0, N%128==0, K%16==0 (true for all our shapes).
#define BM 128
#define BN 128
#define BK 16

__global__ __launch_bounds__(256) void sgemm_bias(
    const float* __restrict__ A, const float* __restrict__ B,
    const float* __restrict__ bias, float* __restrict__ C,
    int M, int N, int K)
{
    __shared__ float As[BK][BM + 4];   // A tile, transposed (k-major)
    __shared__ float Bs[BK][BN + 4];
    const int tid = threadIdx.x;
    const int tr = tid >> 4;      // 0..15
    const int tc = tid & 15;      // 0..15
    const int bm = blockIdx.y, bn = blockIdx.x;
    const float* Ab = A + (size_t)bm * BM * K;

    float acc[8][8];
    #pragma unroll
    for (int i = 0; i < 8; ++i)
        #pragma unroll
        for (int j = 0; j < 8; ++j) acc[i][j] = 0.f;

    for (int k0 = 0; k0 < K; k0 += BK) {
        #pragma unroll
        for (int l = 0; l < 2; ++l) {
            int idx = tid + l * 256;      // 0..511
            int row = idx >> 2;           // 0..127
            int c4  = idx & 3;            // 0..3
            float4 v = *(const float4*)(Ab + (size_t)row * K + k0 + c4 * 4);
            As[c4 * 4 + 0][row] = v.x;
            As[c4 * 4 + 1][row] = v.y;
            As[c4 * 4 + 2][row] = v.z;
            As[c4 * 4 + 3][row] = v.w;
        }
        #pragma unroll
        for (int l = 0; l < 2; ++l) {
            int idx = tid + l * 256;
            int row = idx >> 5;           // 0..15
            int c4  = idx & 31;           // 0..31
            float4 v = *(const float4*)(B + (size_t)(k0 + row) * N + bn * BN + c4 * 4);
            *(float4*)&Bs[row][c4 * 4] = v;
        }
        __syncthreads();
        #pragma unroll
        for (int kk = 0; kk < BK; ++kk) {
            float4 a0 = *(const float4*)&As[kk][tr * 8];
            float4 a1 = *(const float4*)&As[kk][tr * 8 + 4];
            float4 b0 = *(const float4*)&Bs[kk][tc * 8];
            float4 b1 = *(const float4*)&Bs[kk][tc * 8 + 4];
            float av[8] = {a0.x, a0.y, a0.z, a0.w, a1.x, a1.y, a1.z, a1.w};
            float bv[8] = {b0.x, b0.y, b0.z, b0.w, b1.x, b1.y, b1.z, b1.w};
            #pragma unroll
            for (int i = 0; i < 8; ++i)
                #pragma unroll
                for (int j = 0; j < 8; ++j)
                    acc[i][j] += av[i] * bv[j];
        }
        __syncthreads();
    }
    #pragma unroll
    for (int i = 0; i < 8; ++i) {
        size_t row = (size_t)bm * BM + tr * 8 + i;
        #pragma unroll
        for (int j = 0; j < 8; j += 4) {
            int col = bn * BN + tc * 8 + j;
            float4 v = make_float4(acc[i][j], acc[i][j + 1], acc[i][j + 2], acc[i][j + 3]);
            if (bias) {
                v.x += bias[col];     v.y += bias[col + 1];
                v.z += bias[col + 2]; v.w += bias[col + 3];
            }
            *(float4*)(C + row * N + col) = v;
        }
    }
}

// ---------------- fused LSTM step: lin = Xt + h_prev @ Wh + b; gates; c,h update ----
// Block: 64 batch rows x 8 hidden cols (=> 32 lin cols: 4 gates x 8). Grid (128, 2).
#define SBM 64
#define SBN 8
#define SBK 16

__global__ __launch_bounds__(256) void lstm_step(
    const float* __restrict__ Xt,      // [BATCH, GDIM] input-part preactivations (no bias)
    const float* __restrict__ h_prev,  // [BATCH, NH] or nullptr (t==0 -> zeros)
    float* __restrict__ c_state,       // [BATCH, NH] in-place (ignored-as-zero when first)
    const float* __restrict__ Wh,      // [NH, GDIM] recurrent weight rows
    const float* __restrict__ bias,    // [GDIM]
    float* __restrict__ h_out,         // [BATCH, NH]
    int first)
{
    __shared__ float hs[SBK][SBM + 4];      // h tile, k-major
    __shared__ float Ws[SBK][4 * SBN];      // 16 x 32
    __shared__ float lin_s[SBM][4 * SBN + 1];
    const int tid = threadIdx.x;
    const int bn = blockIdx.x;   // 0..127 hidden-col tile
    const int bm = blockIdx.y;   // 0..1 batch tile
    const int rg = tid >> 4;     // 0..15 (4 batch rows each)
    const int cg = tid & 15;     // 0..15 (2 lin cols each)

    float acc[4][2] = {{0.f, 0.f}, {0.f, 0.f}, {0.f, 0.f}, {0.f, 0.f}};

    if (h_prev) {
        for (int k0 = 0; k0 < NH; k0 += SBK) {
            {   // stage h tile (64 x 16), transposed
                int row = tid >> 2;    // 0..63
                int c4  = tid & 3;     // 0..3
                float4 v = *(const float4*)(h_prev + (size_t)(bm * SBM + row) * NH + k0 + c4 * 4);
                hs[c4 * 4 + 0][row] = v.x;
                hs[c4 * 4 + 1][row] = v.y;
                hs[c4 * 4 + 2][row] = v.z;
                hs[c4 * 4 + 3][row] = v.w;
            }
            if (tid < 128) {  // stage W tile: 16 k-rows x (4 gates x 8 cols)
                int k = tid >> 3;      // 0..15
                int p = tid & 7;       // 0..7
                int g = p >> 1, half = p & 1;
                float4 v = *(const float4*)(Wh + (size_t)(k0 + k) * GDIM + g * NH + bn * SBN + half * 4);
                *(float4*)&Ws[k][g * SBN + half * 4] = v;
            }
            __syncthreads();
            #pragma unroll
            for (int kk = 0; kk < SBK; ++kk) {
                float4 a = *(const float4*)&hs[kk][rg * 4];
                float w0v = Ws[kk][cg * 2];
                float w1v = Ws[kk][cg * 2 + 1];
                acc[0][0] += a.x * w0v; acc[0][1] += a.x * w1v;
                acc[1][0] += a.y * w0v; acc[1][1] += a.y * w1v;
                acc[2][0] += a.z * w0v; acc[2][1] += a.z * w1v;
                acc[3][0] += a.w * w0v; acc[3][1] += a.w * w1v;
            }
            __syncthreads();
        }
    }
    // park recurrent lin in LDS so each thread can gather all 4 gates of a column
    #pragma unroll
    for (int i = 0; i < 4; ++i) {
        lin_s[rg * 4 + i][cg * 2 + 0] = acc[i][0];
        lin_s[rg * 4 + i][cg * 2 + 1] = acc[i][1];
    }
    __syncthreads();
    // 512 (b,c) pairs, 2 per thread
    #pragma unroll
    for (int l = 0; l < 2; ++l) {
        int p = tid + l * 256;
        int b = p >> 3;            // 0..63
        int c = p & 7;             // 0..7
        int gb = bm * SBM + b;
        int n  = bn * SBN + c;
        const float* xrow = Xt + (size_t)gb * GDIM;
        float pf = lin_s[b][0 * SBN + c] + xrow[0 * NH + n] + bias[0 * NH + n];
        float pi = lin_s[b][1 * SBN + c] + xrow[1 * NH + n] + bias[1 * NH + n];
        float po = lin_s[b][2 * SBN + c] + xrow[2 * NH + n] + bias[2 * NH + n];
        float pg = lin_s[b][3 * SBN + c] + xrow[3 * NH + n] + bias[3 * NH + n];
        float f  = sigmoidf_(pf);
        float ii = sigmoidf_(pi);
        float oo = sigmoidf_(po);
        float gg = tanhf_(pg);
        float cold = first ? 0.f : c_state[(size_t)gb * NH + n];
        float cn = f * cold + ii * gg;
        float hn = oo * tanhf_(cn);
        c_state[(size_t)gb * NH + n] = cn;
        h_out[(size_t)gb * NH + n]  = hn;
    }
}

extern "C" void kernel_launch(void* const* d_in, const int* in_sizes, int n_in,
                              void* d_out, int out_size, void* d_ws, size_t ws_size,
                              hipStream_t stream)
{
    const float* inputs = (const float*)d_in[0];  // [256,128,256]
    const float* emb    = (const float*)d_in[1];  // [256,512]
    const float* w0     = (const float*)d_in[2];  // [1536,4096]
    const float* b0     = (const float*)d_in[3];  // [4096]
    const float* w1     = (const float*)d_in[4];  // [2048,4096]
    const float* b1     = (const float*)d_in[5];  // [4096]
    const float* outw   = (const float*)d_in[6];  // [1024,256]
    const float* outb   = (const float*)d_in[7];  // [256]
    float* out = (float*)d_out;                   // [32768,256]

    // ---- workspace layout: fixed part + time-chunked buffers sized to ws_size ----
    char* ws = (char*)d_ws;
    size_t off = 0;
    float* Wcomb = (float*)(ws + off); off += (size_t)VOCAB * GDIM * 4;        // 4 MB
    float* Cst0  = (float*)(ws + off); off += (size_t)BATCH * NH * 4;          // 0.5 MB
    float* Cst1  = (float*)(ws + off); off += (size_t)BATCH * NH * 4;          // 0.5 MB

    // choose largest chunk TC dividing 256 that fits:
    // Xc = TC*B*G*4 bytes, plus 4 H chunk buffers of TC*B*NH*4 each.
    int TC = 2;
    for (int cand = 64; cand >= 2; cand >>= 1) {
        size_t need = off + (size_t)cand * BATCH * GDIM * 4
                          + 4 * (size_t)cand * BATCH * NH * 4;
        if (need <= ws_size) { TC = cand; break; }
    }
    const size_t xcElems = (size_t)TC * BATCH * GDIM;
    const size_t hcElems = (size_t)TC * BATCH * NH;
    float* Xc = (float*)(ws + off); off += xcElems * 4;
    float* H0buf[2], * H1buf[2];
    H0buf[0] = (float*)(ws + off); off += hcElems * 4;
    H0buf[1] = (float*)(ws + off); off += hcElems * 4;
    H1buf[0] = (float*)(ws + off); off += hcElems * 4;
    H1buf[1] = (float*)(ws + off); off += hcElems * 4;

    const float* W0h = w0 + (size_t)EDIM * GDIM;   // recurrent rows of layer 0
    const float* W1h = w1 + (size_t)NH * GDIM;     // recurrent rows of layer 1
    const int CB = TC * BATCH;                      // rows per chunk GEMM

    // 1) Wcomb = emb @ W0x  (fold embedding into layer-0 input weights)
    sgemm_bias<<<dim3(GDIM / BN, VOCAB / BM), 256, 0, stream>>>(
        emb, w0, nullptr, Wcomb, VOCAB, GDIM, EDIM);

    const int nChunks = T_STEPS / TC;
    for (int k = 0; k < nChunks; ++k) {
        const int t0 = k * TC;
        const int pp = k & 1;
        float* H0c = H0buf[pp]; const float* H0p = H0buf[pp ^ 1];
        float* H1c = H1buf[pp]; const float* H1p = H1buf[pp ^ 1];

        // X0 chunk = inputs[t0:t0+TC] @ Wcomb
        sgemm_bias<<<dim3(GDIM / BN, CB / BM), 256, 0, stream>>>(
            inputs + (size_t)t0 * BATCH * VOCAB, Wcomb, nullptr, Xc, CB, GDIM, VOCAB);
        // layer-0 recurrence over the chunk
        for (int ts = 0; ts < TC; ++ts) {
            const int t = t0 + ts;
            const float* hp = ts ? (H0c + (size_t)(ts - 1) * BATCH * NH)
                                 : (t0 ? (H0p + (size_t)(TC - 1) * BATCH * NH) : nullptr);
            lstm_step<<<dim3(NH / SBN, BATCH / SBM), 256, 0, stream>>>(
                Xc + (size_t)ts * BATCH * GDIM, hp, Cst0, W0h, b0,
                H0c + (size_t)ts * BATCH * NH, t == 0);
        }
        // X1 chunk = H0 chunk @ W1x  (reuse Xc; X0 chunk is dead)
        sgemm_bias<<<dim3(GDIM / BN, CB / BM), 256, 0, stream>>>(
            H0c, w1, nullptr, Xc, CB, GDIM, NH);
        // layer-1 recurrence over the chunk
        for (int ts = 0; ts < TC; ++ts) {
            const int t = t0 + ts;
            const float* hp = ts ? (H1c + (size_t)(ts - 1) * BATCH * NH)
                                 : (t0 ? (H1p + (size_t)(TC - 1) * BATCH * NH) : nullptr);
            lstm_step<<<dim3(NH / SBN, BATCH / SBM), 256, 0, stream>>>(
                Xc + (size_t)ts * BATCH * GDIM, hp, Cst1, W1h, b1,
                H1c + (size_t)ts * BATCH * NH, t == 0);
        }
        // logits chunk = H1 chunk @ out_w + out_b  -> directly into d_out
        sgemm_bias<<<dim3(VOCAB / BN, CB / BM), 256, 0, stream>>>(
            H1c, outw, outb, out + (size_t)t0 * BATCH * VOCAB, CB, VOCAB, NH);
    }
}

// Round 3
// 11936.698 us; speedup vs baseline: 3.4946x; 3.4946x over previous
//
#include <hip/hip_runtime.h>
#include <hip/hip_bf16.h>
#include <cstdint>
#include <cstddef>

#define T_STEPS 256
#define BATCH   128
#define VOCAB   256
#define EDIM    512
#define NH      1024
#define GDIM    4096   // 4*NH

typedef __attribute__((ext_vector_type(8))) short short8;
typedef __attribute__((ext_vector_type(4))) float floatx4;

__device__ __forceinline__ float sigmoidf_(float x) { return 1.0f / (1.0f + __expf(-x)); }
__device__ __forceinline__ float tanhf_(float x)    { return 1.0f - 2.0f / (__expf(2.0f * x) + 1.0f); }

// ---------------- fp32 GEMM (prep only: Wcomb = emb @ W0x) ----------------
#define BM 128
#define BN 128
#define BK 16
__global__ __launch_bounds__(256) void sgemm_f32(
    const float* __restrict__ A, const float* __restrict__ B,
    float* __restrict__ C, int M, int N, int K)
{
    __shared__ float As[BK][BM + 4];
    __shared__ float Bs[BK][BN + 4];
    const int tid = threadIdx.x;
    const int tr = tid >> 4, tc = tid & 15;
    const int bm = blockIdx.y, bn = blockIdx.x;
    const float* Ab = A + (size_t)bm * BM * K;
    float acc[8][8];
    #pragma unroll
    for (int i = 0; i < 8; ++i)
        #pragma unroll
        for (int j = 0; j < 8; ++j) acc[i][j] = 0.f;
    for (int k0 = 0; k0 < K; k0 += BK) {
        #pragma unroll
        for (int l = 0; l < 2; ++l) {
            int idx = tid + l * 256;
            int row = idx >> 2, c4 = idx & 3;
            float4 v = *(const float4*)(Ab + (size_t)row * K + k0 + c4 * 4);
            As[c4 * 4 + 0][row] = v.x; As[c4 * 4 + 1][row] = v.y;
            As[c4 * 4 + 2][row] = v.z; As[c4 * 4 + 3][row] = v.w;
        }
        #pragma unroll
        for (int l = 0; l < 2; ++l) {
            int idx = tid + l * 256;
            int row = idx >> 5, c4 = idx & 31;
            *(float4*)&Bs[row][c4 * 4] = *(const float4*)(B + (size_t)(k0 + row) * N + bn * BN + c4 * 4);
        }
        __syncthreads();
        #pragma unroll
        for (int kk = 0; kk < BK; ++kk) {
            float4 a0 = *(const float4*)&As[kk][tr * 8];
            float4 a1 = *(const float4*)&As[kk][tr * 8 + 4];
            float4 b0 = *(const float4*)&Bs[kk][tc * 8];
            float4 b1 = *(const float4*)&Bs[kk][tc * 8 + 4];
            float av[8] = {a0.x, a0.y, a0.z, a0.w, a1.x, a1.y, a1.z, a1.w};
            float bv[8] = {b0.x, b0.y, b0.z, b0.w, b1.x, b1.y, b1.z, b1.w};
            #pragma unroll
            for (int i = 0; i < 8; ++i)
                #pragma unroll
                for (int j = 0; j < 8; ++j) acc[i][j] += av[i] * bv[j];
        }
        __syncthreads();
    }
    #pragma unroll
    for (int i = 0; i < 8; ++i) {
        size_t row = (size_t)bm * BM + tr * 8 + i;
        #pragma unroll
        for (int j = 0; j < 8; j += 4) {
            int col = bn * BN + tc * 8 + j;
            *(float4*)(C + row * N + col) =
                make_float4(acc[i][j], acc[i][j+1], acc[i][j+2], acc[i][j+3]);
        }
    }
}

// ---------------- transpose + fp32->bf16: dst[C][R] <- src[R][C] ----------------
__global__ __launch_bounds__(256) void transpose_to_bf16(
    const float* __restrict__ src, __hip_bfloat16* __restrict__ dst, int R, int C)
{
    __shared__ float t[32][33];
    int x = blockIdx.x * 32 + threadIdx.x;
    #pragma unroll
    for (int i = 0; i < 4; ++i) {
        int y = blockIdx.y * 32 + threadIdx.y + i * 8;
        t[threadIdx.y + i * 8][threadIdx.x] = src[(size_t)y * C + x];
    }
    __syncthreads();
    int x2 = blockIdx.y * 32 + threadIdx.x;
    #pragma unroll
    for (int i = 0; i < 4; ++i) {
        int y2 = blockIdx.x * 32 + threadIdx.y + i * 8;
        dst[(size_t)y2 * R + x2] = __float2bfloat16(t[threadIdx.x][threadIdx.y + i * 8]);
    }
}

// ---------------- fp32 -> bf16 convert (no transpose) ----------------
__global__ __launch_bounds__(256) void convert_to_bf16(
    const float* __restrict__ src, __hip_bfloat16* __restrict__ dst, size_t n4)
{
    size_t i = (size_t)blockIdx.x * 256 + threadIdx.x;
    if (i < n4) {
        float4 v = *(const float4*)(src + i * 4);
        __hip_bfloat16 o[4] = {__float2bfloat16(v.x), __float2bfloat16(v.y),
                               __float2bfloat16(v.z), __float2bfloat16(v.w)};
        *(uint2*)(dst + i * 4) = *(uint2*)o;
    }
}

// ---------------- bf16 MFMA GEMM: C[M][N] f32 = A[M][K] @ Bt[N][K] (+bias) ------
// 128x128 tile, BK=32, 256 threads = 4 waves in 2x2, each wave 64x64 (4x4 MFMA).
#define GKP 40   // padded LDS k-stride (bf16 elems)
__global__ __launch_bounds__(256) void gemm_bt(
    const __hip_bfloat16* __restrict__ A, const __hip_bfloat16* __restrict__ Bt,
    const float* __restrict__ bias, float* __restrict__ C, int M, int N, int K)
{
    __shared__ __hip_bfloat16 As[128 * GKP];
    __shared__ __hip_bfloat16 Bs[128 * GKP];
    const int tid = threadIdx.x;
    const int wave = tid >> 6, lane = tid & 63;
    const int quad = lane >> 4, l16 = lane & 15;
    const int wm = (wave >> 1) * 64, wn = (wave & 1) * 64;
    const size_t Arow0 = (size_t)blockIdx.y * 128;
    const size_t Brow0 = (size_t)blockIdx.x * 128;
    floatx4 acc[4][4];
    #pragma unroll
    for (int i = 0; i < 4; ++i)
        #pragma unroll
        for (int j = 0; j < 4; ++j) acc[i][j] = (floatx4)0.f;

    for (int k0 = 0; k0 < K; k0 += 32) {
        #pragma unroll
        for (int l = 0; l < 2; ++l) {
            int idx = tid + l * 256;           // 0..511
            int row = idx >> 2, seg = idx & 3; // 128 rows x 4 segs of 8 bf16
            *(uint4*)(As + row * GKP + seg * 8) =
                *(const uint4*)(A + (Arow0 + row) * K + k0 + seg * 8);
            *(uint4*)(Bs + row * GKP + seg * 8) =
                *(const uint4*)(Bt + (Brow0 + row) * K + k0 + seg * 8);
        }
        __syncthreads();
        short8 af[4], bf[4];
        #pragma unroll
        for (int i = 0; i < 4; ++i)
            af[i] = *(const short8*)(As + (wm + i * 16 + l16) * GKP + quad * 8);
        #pragma unroll
        for (int j = 0; j < 4; ++j)
            bf[j] = *(const short8*)(Bs + (wn + j * 16 + l16) * GKP + quad * 8);
        #pragma unroll
        for (int i = 0; i < 4; ++i)
            #pragma unroll
            for (int j = 0; j < 4; ++j)
                acc[i][j] = __builtin_amdgcn_mfma_f32_16x16x32_bf16(af[i], bf[j], acc[i][j], 0, 0, 0);
        __syncthreads();
    }
    #pragma unroll
    for (int i = 0; i < 4; ++i)
        #pragma unroll
        for (int j = 0; j < 4; ++j) {
            int col = (int)Brow0 + wn + j * 16 + l16;
            float bv = bias ? bias[col] : 0.f;
            #pragma unroll
            for (int r = 0; r < 4; ++r) {
                size_t row = Arow0 + wm + i * 16 + quad * 4 + r;
                C[row * N + col] = acc[i][j][r] + bv;
            }
        }
}

// ---------------- MFMA LSTM step ----------------
// lin[128][4096] = h_prev @ Wh (+ Xt which already holds x-part + bias); gates fused.
// Grid: 64 blocks; block bn owns hidden cols [bn*16, bn*16+16) across ALL 4 gates.
// 256 threads = 4 waves; wave w owns batch rows [w*32, w*32+32).
// C/D layout (col=lane&15, row=quad*4+reg) is identical across the 4 gate tiles,
// so f/i/o/g for one (b,n) sit in the same lane & reg -> in-register gate fusion.
__global__ __launch_bounds__(256) void lstm_step_mfma(
    const float* __restrict__ Xt,            // [128][4096] x-part + bias
    const __hip_bfloat16* __restrict__ h_prev, // [128][1024] bf16 or null
    float* __restrict__ c_state,             // [128][1024] f32
    const __hip_bfloat16* __restrict__ Wht,  // [4096][1024] bf16 (n-major, k-contig)
    __hip_bfloat16* __restrict__ h_out,      // [128][1024] bf16
    int first)
{
    __shared__ __hip_bfloat16 hs[128 * GKP];
    __shared__ __hip_bfloat16 Ws[64 * GKP];
    const int tid = threadIdx.x;
    const int wave = tid >> 6, lane = tid & 63;
    const int quad = lane >> 4, l16 = lane & 15;
    const int bn = blockIdx.x;
    floatx4 acc[2][4];
    #pragma unroll
    for (int i = 0; i < 2; ++i)
        #pragma unroll
        for (int g = 0; g < 4; ++g) acc[i][g] = (floatx4)0.f;

    if (h_prev) {
        for (int k0 = 0; k0 < NH; k0 += 32) {
            #pragma unroll
            for (int l = 0; l < 2; ++l) {
                int idx = tid + l * 256;
                int row = idx >> 2, seg = idx & 3;
                *(uint4*)(hs + row * GKP + seg * 8) =
                    *(const uint4*)(h_prev + (size_t)row * NH + k0 + seg * 8);
            }
            {   // 64 weight rows (4 gates x 16 cols), 4 segs of 8
                int wrow = tid >> 2, seg = tid & 3;
                int g = wrow >> 4, hc = wrow & 15;
                size_t grow = (size_t)g * NH + (size_t)bn * 16 + hc;
                *(uint4*)(Ws + wrow * GKP + seg * 8) =
                    *(const uint4*)(Wht + grow * NH + k0 + seg * 8);
            }
            __syncthreads();
            short8 af[2], bf[4];
            #pragma unroll
            for (int i = 0; i < 2; ++i)
                af[i] = *(const short8*)(hs + (wave * 32 + i * 16 + l16) * GKP + quad * 8);
            #pragma unroll
            for (int g = 0; g < 4; ++g)
                bf[g] = *(const short8*)(Ws + (g * 16 + l16) * GKP + quad * 8);
            #pragma unroll
            for (int i = 0; i < 2; ++i)
                #pragma unroll
                for (int g = 0; g < 4; ++g)
                    acc[i][g] = __builtin_amdgcn_mfma_f32_16x16x32_bf16(af[i], bf[g], acc[i][g], 0, 0, 0);
            __syncthreads();
        }
    }
    const int n = bn * 16 + l16;
    #pragma unroll
    for (int i = 0; i < 2; ++i) {
        #pragma unroll
        for (int r = 0; r < 4; ++r) {
            int b = wave * 32 + i * 16 + quad * 4 + r;
            const float* xrow = Xt + (size_t)b * GDIM;
            float pf = acc[i][0][r] + xrow[0 * NH + n];
            float pi = acc[i][1][r] + xrow[1 * NH + n];
            float po = acc[i][2][r] + xrow[2 * NH + n];
            float pg = acc[i][3][r] + xrow[3 * NH + n];
            float f  = sigmoidf_(pf);
            float ig = sigmoidf_(pi);
            float oo = sigmoidf_(po);
            float gg = tanhf_(pg);
            float cold = first ? 0.f : c_state[(size_t)b * NH + n];
            float cn = f * cold + ig * gg;
            float hn = oo * tanhf_(cn);
            c_state[(size_t)b * NH + n] = cn;
            h_out[(size_t)b * NH + n]  = __float2bfloat16(hn);
        }
    }
}

extern "C" void kernel_launch(void* const* d_in, const int* in_sizes, int n_in,
                              void* d_out, int out_size, void* d_ws, size_t ws_size,
                              hipStream_t stream)
{
    const float* inputs = (const float*)d_in[0];  // [256,128,256]
    const float* emb    = (const float*)d_in[1];  // [256,512]
    const float* w0     = (const float*)d_in[2];  // [1536,4096]
    const float* b0     = (const float*)d_in[3];  // [4096]
    const float* w1     = (const float*)d_in[4];  // [2048,4096]
    const float* b1     = (const float*)d_in[5];  // [4096]
    const float* outw   = (const float*)d_in[6];  // [1024,256]
    const float* outb   = (const float*)d_in[7];  // [256]
    float* out = (float*)d_out;                   // [32768,256]

    char* ws = (char*)d_ws;
    size_t off = 0;
    float* Wcomb = (float*)(ws + off); off += (size_t)VOCAB * GDIM * 4;           // 4 MB
    __hip_bfloat16* Wcombt = (__hip_bfloat16*)(ws + off); off += (size_t)VOCAB * GDIM * 2;  // 2 MB
    __hip_bfloat16* W1xt   = (__hip_bfloat16*)(ws + off); off += (size_t)NH * GDIM * 2;     // 8 MB
    __hip_bfloat16* W0ht   = (__hip_bfloat16*)(ws + off); off += (size_t)NH * GDIM * 2;     // 8 MB
    __hip_bfloat16* W1ht   = (__hip_bfloat16*)(ws + off); off += (size_t)NH * GDIM * 2;     // 8 MB
    __hip_bfloat16* outwt  = (__hip_bfloat16*)(ws + off); off += (size_t)NH * VOCAB * 2;    // 0.5 MB
    __hip_bfloat16* inbf   = (__hip_bfloat16*)(ws + off); off += (size_t)T_STEPS * BATCH * VOCAB * 2; // 16 MB
    float* Cst0 = (float*)(ws + off); off += (size_t)BATCH * NH * 4;
    float* Cst1 = (float*)(ws + off); off += (size_t)BATCH * NH * 4;

    // chunk sizing: Xc fp32 (TC*2MB) + 4 bf16 H buffers (TC*0.25MB each)
    int TC = 1;
    for (int cand = 64; cand >= 1; cand >>= 1) {
        size_t need = off + (size_t)cand * BATCH * GDIM * 4
                          + 4 * (size_t)cand * BATCH * NH * 2;
        if (need <= ws_size) { TC = cand; break; }
    }
    float* Xc = (float*)(ws + off); off += (size_t)TC * BATCH * GDIM * 4;
    __hip_bfloat16* H0buf[2], *H1buf[2];
    const size_t hcElems = (size_t)TC * BATCH * NH;
    H0buf[0] = (__hip_bfloat16*)(ws + off); off += hcElems * 2;
    H0buf[1] = (__hip_bfloat16*)(ws + off); off += hcElems * 2;
    H1buf[0] = (__hip_bfloat16*)(ws + off); off += hcElems * 2;
    H1buf[1] = (__hip_bfloat16*)(ws + off); off += hcElems * 2;

    const int CB = TC * BATCH;

    // ---- prep (runs every launch; deterministic) ----
    // Wcomb = emb @ W0x  (fp32)
    sgemm_f32<<<dim3(GDIM / BN, VOCAB / BM), 256, 0, stream>>>(
        emb, w0, Wcomb, VOCAB, GDIM, EDIM);
    // transposed bf16 weights ([N][K] layouts)
    transpose_to_bf16<<<dim3(GDIM / 32, VOCAB / 32), dim3(32, 8), 0, stream>>>(
        Wcomb, Wcombt, VOCAB, GDIM);
    transpose_to_bf16<<<dim3(GDIM / 32, NH / 32), dim3(32, 8), 0, stream>>>(
        w1, W1xt, NH, GDIM);
    transpose_to_bf16<<<dim3(GDIM / 32, NH / 32), dim3(32, 8), 0, stream>>>(
        w0 + (size_t)EDIM * GDIM, W0ht, NH, GDIM);
    transpose_to_bf16<<<dim3(GDIM / 32, NH / 32), dim3(32, 8), 0, stream>>>(
        w1 + (size_t)NH * GDIM, W1ht, NH, GDIM);
    transpose_to_bf16<<<dim3(VOCAB / 32, NH / 32), dim3(32, 8), 0, stream>>>(
        outw, outwt, NH, VOCAB);
    {   // inputs -> bf16
        size_t n4 = (size_t)T_STEPS * BATCH * VOCAB / 4;
        convert_to_bf16<<<(int)((n4 + 255) / 256), 256, 0, stream>>>(inputs, inbf, n4);
    }

    // ---- main chunked pipeline ----
    const int nChunks = T_STEPS / TC;
    for (int k = 0; k < nChunks; ++k) {
        const int t0 = k * TC;
        const int pp = k & 1;
        __hip_bfloat16* H0c = H0buf[pp]; const __hip_bfloat16* H0p = H0buf[pp ^ 1];
        __hip_bfloat16* H1c = H1buf[pp]; const __hip_bfloat16* H1p = H1buf[pp ^ 1];

        // X0 chunk = inputs_bf[t0:t0+TC] @ Wcombt^T + b0
        gemm_bt<<<dim3(GDIM / 128, CB / 128), 256, 0, stream>>>(
            inbf + (size_t)t0 * BATCH * VOCAB, Wcombt, b0, Xc, CB, GDIM, VOCAB);
        for (int ts = 0; ts < TC; ++ts) {
            const int t = t0 + ts;
            const __hip_bfloat16* hp = ts ? (H0c + (size_t)(ts - 1) * BATCH * NH)
                                          : (t0 ? (H0p + (size_t)(TC - 1) * BATCH * NH) : nullptr);
            lstm_step_mfma<<<NH / 16, 256, 0, stream>>>(
                Xc + (size_t)ts * BATCH * GDIM, hp, Cst0, W0ht,
                H0c + (size_t)ts * BATCH * NH, t == 0);
        }
        // X1 chunk = H0 chunk @ W1xt^T + b1
        gemm_bt<<<dim3(GDIM / 128, CB / 128), 256, 0, stream>>>(
            H0c, W1xt, b1, Xc, CB, GDIM, NH);
        for (int ts = 0; ts < TC; ++ts) {
            const int t = t0 + ts;
            const __hip_bfloat16* hp = ts ? (H1c + (size_t)(ts - 1) * BATCH * NH)
                                          : (t0 ? (H1p + (size_t)(TC - 1) * BATCH * NH) : nullptr);
            lstm_step_mfma<<<NH / 16, 256, 0, stream>>>(
                Xc + (size_t)ts * BATCH * GDIM, hp, Cst1, W1ht,
                H1c + (size_t)ts * BATCH * NH, t == 0);
        }
        // logits chunk = H1 chunk @ outwt^T + outb -> d_out
        gemm_bt<<<dim3(VOCAB / 128, CB / 128), 256, 0, stream>>>(
            H1c, outwt, outb, out + (size_t)t0 * BATCH * VOCAB, CB, VOCAB, NH);
    }
}

// Round 4
// 7599.350 us; speedup vs baseline: 5.4891x; 1.5708x over previous
//
#include <hip/hip_runtime.h>
#include <hip/hip_bf16.h>
#include <cstdint>
#include <cstddef>

#define T_STEPS 256
#define BATCH   128
#define VOCAB   256
#define EDIM    512
#define NH      1024
#define GDIM    4096   // 4*NH
#define KP0     1280   // layer0 packed K: 256 (x) + 1024 (h)
#define KP1     2048   // layer1 packed K: 1024 (h0) + 1024 (h1)

typedef __attribute__((ext_vector_type(8))) short short8;
typedef __attribute__((ext_vector_type(4))) float floatx4;

__device__ __forceinline__ float sigmoidf_(float x) { return 1.0f / (1.0f + __expf(-x)); }
__device__ __forceinline__ float tanhf_(float x)    { return 1.0f - 2.0f / (__expf(2.0f * x) + 1.0f); }

typedef __attribute__((address_space(1))) const unsigned int guint;
typedef __attribute__((address_space(3))) unsigned int luint;
__device__ __forceinline__ void load_lds16(const void* g, void* l) {
    // async global->LDS, 16B per lane; LDS dest is wave-uniform base + lane*16
    __builtin_amdgcn_global_load_lds((guint*)g, (luint*)l, 16, 0, 0);
}

// ---------------- fp32 GEMM (prep only: Wcomb = emb @ W0x) ----------------
#define BM 128
#define BN 128
#define BK 16
__global__ __launch_bounds__(256) void sgemm_f32(
    const float* __restrict__ A, const float* __restrict__ B,
    float* __restrict__ C, int M, int N, int K)
{
    __shared__ float As[BK][BM + 4];
    __shared__ float Bs[BK][BN + 4];
    const int tid = threadIdx.x;
    const int tr = tid >> 4, tc = tid & 15;
    const int bm = blockIdx.y, bn = blockIdx.x;
    const float* Ab = A + (size_t)bm * BM * K;
    float acc[8][8];
    #pragma unroll
    for (int i = 0; i < 8; ++i)
        #pragma unroll
        for (int j = 0; j < 8; ++j) acc[i][j] = 0.f;
    for (int k0 = 0; k0 < K; k0 += BK) {
        #pragma unroll
        for (int l = 0; l < 2; ++l) {
            int idx = tid + l * 256;
            int row = idx >> 2, c4 = idx & 3;
            float4 v = *(const float4*)(Ab + (size_t)row * K + k0 + c4 * 4);
            As[c4 * 4 + 0][row] = v.x; As[c4 * 4 + 1][row] = v.y;
            As[c4 * 4 + 2][row] = v.z; As[c4 * 4 + 3][row] = v.w;
        }
        #pragma unroll
        for (int l = 0; l < 2; ++l) {
            int idx = tid + l * 256;
            int row = idx >> 5, c4 = idx & 31;
            *(float4*)&Bs[row][c4 * 4] = *(const float4*)(B + (size_t)(k0 + row) * N + bn * BN + c4 * 4);
        }
        __syncthreads();
        #pragma unroll
        for (int kk = 0; kk < BK; ++kk) {
            float4 a0 = *(const float4*)&As[kk][tr * 8];
            float4 a1 = *(const float4*)&As[kk][tr * 8 + 4];
            float4 b0 = *(const float4*)&Bs[kk][tc * 8];
            float4 b1 = *(const float4*)&Bs[kk][tc * 8 + 4];
            float av[8] = {a0.x, a0.y, a0.z, a0.w, a1.x, a1.y, a1.z, a1.w};
            float bv[8] = {b0.x, b0.y, b0.z, b0.w, b1.x, b1.y, b1.z, b1.w};
            #pragma unroll
            for (int i = 0; i < 8; ++i)
                #pragma unroll
                for (int j = 0; j < 8; ++j) acc[i][j] += av[i] * bv[j];
        }
        __syncthreads();
    }
    #pragma unroll
    for (int i = 0; i < 8; ++i) {
        size_t row = (size_t)bm * BM + tr * 8 + i;
        #pragma unroll
        for (int j = 0; j < 8; j += 4) {
            int col = bn * BN + tc * 8 + j;
            *(float4*)(C + row * N + col) =
                make_float4(acc[i][j], acc[i][j+1], acc[i][j+2], acc[i][j+3]);
        }
    }
}

// ---------------- transpose + fp32->bf16: dst[C][R] <- src[R][C] ----------------
__global__ __launch_bounds__(256) void transpose_to_bf16(
    const float* __restrict__ src, __hip_bfloat16* __restrict__ dst, int R, int C)
{
    __shared__ float t[32][33];
    int x = blockIdx.x * 32 + threadIdx.x;
    #pragma unroll
    for (int i = 0; i < 4; ++i) {
        int y = blockIdx.y * 32 + threadIdx.y + i * 8;
        t[threadIdx.y + i * 8][threadIdx.x] = src[(size_t)y * C + x];
    }
    __syncthreads();
    int x2 = blockIdx.y * 32 + threadIdx.x;
    #pragma unroll
    for (int i = 0; i < 4; ++i) {
        int y2 = blockIdx.x * 32 + threadIdx.y + i * 8;
        dst[(size_t)y2 * R + x2] = __float2bfloat16(t[threadIdx.x][threadIdx.y + i * 8]);
    }
}

// ------- fused transpose-pack: fp32 src [Ksrc][4096] -> bf16 block-slice layout ----
// dst row index: j*32 + rr, rr = (g>>1)*16 + (g&1)*8 + c8, lincol = g*1024 + j*8 + c8.
// dst[row][koff + k] with row stride KP. Gate tiles pack as [f|i], [o|g].
__global__ __launch_bounds__(256) void pack_w(
    const float* __restrict__ src, __hip_bfloat16* __restrict__ dst,
    int koff, int KP)
{
    __shared__ float t[32][33];
    int x = blockIdx.x * 32 + threadIdx.x;   // lincol
    #pragma unroll
    for (int i = 0; i < 4; ++i) {
        int y = blockIdx.y * 32 + threadIdx.y + i * 8;   // k
        t[threadIdx.y + i * 8][threadIdx.x] = src[(size_t)y * GDIM + x];
    }
    __syncthreads();
    int k = blockIdx.y * 32 + threadIdx.x;
    #pragma unroll
    for (int i = 0; i < 4; ++i) {
        int lincol = blockIdx.x * 32 + threadIdx.y + i * 8;
        int g = lincol >> 10, n = lincol & 1023;
        int j = n >> 3, c8 = n & 7;
        int rr = (g >> 1) * 16 + (g & 1) * 8 + c8;
        dst[(size_t)(j * 32 + rr) * KP + koff + k] =
            __float2bfloat16(t[threadIdx.x][threadIdx.y + i * 8]);
    }
}

// ---------------- fp32 -> bf16 convert ----------------
__global__ __launch_bounds__(256) void convert_to_bf16(
    const float* __restrict__ src, __hip_bfloat16* __restrict__ dst, size_t n4)
{
    size_t i = (size_t)blockIdx.x * 256 + threadIdx.x;
    if (i < n4) {
        float4 v = *(const float4*)(src + i * 4);
        __hip_bfloat16 o[4] = {__float2bfloat16(v.x), __float2bfloat16(v.y),
                               __float2bfloat16(v.z), __float2bfloat16(v.w)};
        *(uint2*)(dst + i * 4) = *(uint2*)o;
    }
}

// ---------------- bf16 MFMA GEMM: C[M][N] f32 = A[M][K] @ Bt[N][K] (+bias) ------
#define GKP 40
__global__ __launch_bounds__(256) void gemm_bt(
    const __hip_bfloat16* __restrict__ A, const __hip_bfloat16* __restrict__ Bt,
    const float* __restrict__ bias, float* __restrict__ C, int M, int N, int K)
{
    __shared__ __hip_bfloat16 As[128 * GKP];
    __shared__ __hip_bfloat16 Bs[128 * GKP];
    const int tid = threadIdx.x;
    const int wave = tid >> 6, lane = tid & 63;
    const int quad = lane >> 4, l16 = lane & 15;
    const int wm = (wave >> 1) * 64, wn = (wave & 1) * 64;
    const size_t Arow0 = (size_t)blockIdx.y * 128;
    const size_t Brow0 = (size_t)blockIdx.x * 128;
    floatx4 acc[4][4];
    #pragma unroll
    for (int i = 0; i < 4; ++i)
        #pragma unroll
        for (int j = 0; j < 4; ++j) acc[i][j] = (floatx4)0.f;

    for (int k0 = 0; k0 < K; k0 += 32) {
        #pragma unroll
        for (int l = 0; l < 2; ++l) {
            int idx = tid + l * 256;
            int row = idx >> 2, seg = idx & 3;
            *(uint4*)(As + row * GKP + seg * 8) =
                *(const uint4*)(A + (Arow0 + row) * K + k0 + seg * 8);
            *(uint4*)(Bs + row * GKP + seg * 8) =
                *(const uint4*)(Bt + (Brow0 + row) * K + k0 + seg * 8);
        }
        __syncthreads();
        short8 af[4], bf[4];
        #pragma unroll
        for (int i = 0; i < 4; ++i)
            af[i] = *(const short8*)(As + (wm + i * 16 + l16) * GKP + quad * 8);
        #pragma unroll
        for (int j = 0; j < 4; ++j)
            bf[j] = *(const short8*)(Bs + (wn + j * 16 + l16) * GKP + quad * 8);
        #pragma unroll
        for (int i = 0; i < 4; ++i)
            #pragma unroll
            for (int j = 0; j < 4; ++j)
                acc[i][j] = __builtin_amdgcn_mfma_f32_16x16x32_bf16(af[i], bf[j], acc[i][j], 0, 0, 0);
        __syncthreads();
    }
    #pragma unroll
    for (int i = 0; i < 4; ++i)
        #pragma unroll
        for (int j = 0; j < 4; ++j) {
            int col = (int)Brow0 + wn + j * 16 + l16;
            float bv = bias ? bias[col] : 0.f;
            #pragma unroll
            for (int r = 0; r < 4; ++r) {
                size_t row = Arow0 + wm + i * 16 + quad * 4 + r;
                C[row * N + col] = acc[i][j][r] + bv;
            }
        }
}

// ---------------- diagonal fused LSTM step ----------------
// Dispatch d: even blocks (layer0) compute h0[d] (d<256); odd blocks (layer1)
// compute h1[d-1] (d>=1). 128 blocks per layer, each owns 8 hidden cols
// = 32 lin cols packed as 2 MFMA n-tiles [f|i], [o|g]. 512 threads = 8 waves,
// wave w owns batch rows [16w,16w+16). Double-buffered global_load_lds staging.
__global__ __launch_bounds__(512) void lstm_diag(
    const __hip_bfloat16* __restrict__ inbf,   // [256][128][256]
    const __hip_bfloat16* __restrict__ Wpack0, // [128*32][1280]
    const __hip_bfloat16* __restrict__ Wpack1, // [128*32][2048]
    const float* __restrict__ b0, const float* __restrict__ b1,
    __hip_bfloat16* __restrict__ h0_cur,       // h0[d]
    const __hip_bfloat16* __restrict__ h0_prev,// h0[d-1]
    float* __restrict__ c0, float* __restrict__ c1,
    __hip_bfloat16* __restrict__ H1all,        // [256][128][1024]
    int d)
{
    const int layer = blockIdx.x & 1;
    const int j = blockIdx.x >> 1;
    if (layer == 0 && d >= T_STEPS) return;
    if (layer == 1 && d == 0) return;

    __shared__ __attribute__((aligned(16))) __hip_bfloat16 Abuf[2][BATCH * 32];
    __shared__ __attribute__((aligned(16))) __hip_bfloat16 Bbuf[2][32 * 32];

    const int tid = threadIdx.x;
    const int wave = tid >> 6, lane = tid & 63;
    const int quad = lane >> 4, l16 = lane & 15;

    int nk, KP, A0stride, A0steps;
    const __hip_bfloat16 *Wp, *A0base, *A1base;
    const float* bb; float* cst; __hip_bfloat16* hout;
    bool first;
    if (layer == 0) {
        first = (d == 0);
        nk = first ? 8 : 40;
        Wp = Wpack0 + (size_t)j * 32 * KP0; KP = KP0;
        bb = b0; cst = c0;
        A0base = inbf + (size_t)d * (BATCH * VOCAB); A0stride = VOCAB; A0steps = 8;
        A1base = h0_prev;
        hout = h0_cur;
    } else {
        first = (d == 1);
        nk = first ? 32 : 64;
        Wp = Wpack1 + (size_t)j * 32 * KP1; KP = KP1;
        bb = b1; cst = c1;
        A0base = h0_prev; A0stride = NH; A0steps = 32;
        A1base = H1all + (size_t)(d - 2) * (BATCH * NH);
        hout = H1all + (size_t)(d - 1) * (BATCH * NH);
    }

    const int srow = 16 * wave + (lane >> 2);   // staging row for this lane
    const int skseg = (lane & 3) * 8;

    #define STAGE_A(s, buf) do { \
        const __hip_bfloat16* base_; int stride_, kk_; \
        if ((s) < A0steps) { base_ = A0base; stride_ = A0stride; kk_ = (s) * 32; } \
        else { base_ = A1base; stride_ = NH; kk_ = ((s) - A0steps) * 32; } \
        load_lds16(base_ + (size_t)srow * stride_ + kk_ + skseg, \
                   &Abuf[buf][16 * wave * 32]); \
    } while (0)
    #define STAGE_B(s, buf) do { \
        if (wave < 2) \
            load_lds16(Wp + (size_t)srow * KP + (s) * 32 + skseg, \
                       &Bbuf[buf][16 * wave * 32]); \
    } while (0)

    const int cc = j * 8 + (l16 & 7);   // hidden col
    float bv0 = bb[((l16 < 8) ? 0 : 1) * NH + cc];
    float bv1 = bb[((l16 < 8) ? 2 : 3) * NH + cc];
    floatx4 acc0 = {bv0, bv0, bv0, bv0};
    floatx4 acc1 = {bv1, bv1, bv1, bv1};

    STAGE_A(0, 0); STAGE_B(0, 0);
    __syncthreads();
    for (int s = 0; s < nk; ++s) {
        int cur = s & 1, nxt = cur ^ 1;
        if (s + 1 < nk) { STAGE_A(s + 1, nxt); STAGE_B(s + 1, nxt); }
        short8 af  = *(const short8*)&Abuf[cur][(16 * wave + l16) * 32 + quad * 8];
        short8 bf0 = *(const short8*)&Bbuf[cur][(l16) * 32 + quad * 8];
        short8 bf1 = *(const short8*)&Bbuf[cur][(16 + l16) * 32 + quad * 8];
        acc0 = __builtin_amdgcn_mfma_f32_16x16x32_bf16(af, bf0, acc0, 0, 0, 0);
        acc1 = __builtin_amdgcn_mfma_f32_16x16x32_bf16(af, bf1, acc1, 0, 0, 0);
        __syncthreads();
    }

    // epilogue: lanes l16<8 hold (f,o), lanes l16>=8 hold (i,g) for col cc.
    #pragma unroll
    for (int r = 0; r < 4; ++r) {
        float a0 = acc0[r], a1 = acc1[r];
        float p0 = __shfl_xor(a0, 8, 64);
        float p1 = __shfl_xor(a1, 8, 64);
        if (l16 < 8) {
            int b = 16 * wave + quad * 4 + r;
            float f  = sigmoidf_(a0);
            float ig = sigmoidf_(p0);
            float oo = sigmoidf_(a1);
            float gg = tanhf_(p1);
            size_t idx = (size_t)b * NH + cc;
            float cold = first ? 0.f : cst[idx];
            float cn = f * cold + ig * gg;
            float hn = oo * tanhf_(cn);
            cst[idx] = cn;
            hout[idx] = __float2bfloat16(hn);
        }
    }
    #undef STAGE_A
    #undef STAGE_B
}

extern "C" void kernel_launch(void* const* d_in, const int* in_sizes, int n_in,
                              void* d_out, int out_size, void* d_ws, size_t ws_size,
                              hipStream_t stream)
{
    const float* inputs = (const float*)d_in[0];  // [256,128,256]
    const float* emb    = (const float*)d_in[1];  // [256,512]
    const float* w0     = (const float*)d_in[2];  // [1536,4096]
    const float* b0     = (const float*)d_in[3];  // [4096]
    const float* w1     = (const float*)d_in[4];  // [2048,4096]
    const float* b1     = (const float*)d_in[5];  // [4096]
    const float* outw   = (const float*)d_in[6];  // [1024,256]
    const float* outb   = (const float*)d_in[7];  // [256]
    float* out = (float*)d_out;                   // [32768,256]

    char* ws = (char*)d_ws;
    size_t off = 0;
    auto take = [&](size_t bytes) { char* p = ws + off; off += (bytes + 255) & ~(size_t)255; return p; };
    float* Wcomb = (float*)take((size_t)VOCAB * GDIM * 4);                    // 4 MB
    __hip_bfloat16* Wpack0 = (__hip_bfloat16*)take((size_t)128 * 32 * KP0 * 2); // 10.5 MB
    __hip_bfloat16* Wpack1 = (__hip_bfloat16*)take((size_t)128 * 32 * KP1 * 2); // 16.8 MB
    __hip_bfloat16* outwt  = (__hip_bfloat16*)take((size_t)NH * VOCAB * 2);     // 0.5 MB
    __hip_bfloat16* inbf   = (__hip_bfloat16*)take((size_t)T_STEPS * BATCH * VOCAB * 2); // 16 MB
    __hip_bfloat16* h0pp0  = (__hip_bfloat16*)take((size_t)BATCH * NH * 2);
    __hip_bfloat16* h0pp1  = (__hip_bfloat16*)take((size_t)BATCH * NH * 2);
    float* c0 = (float*)take((size_t)BATCH * NH * 4);
    float* c1 = (float*)take((size_t)BATCH * NH * 4);
    __hip_bfloat16* H1all  = (__hip_bfloat16*)take((size_t)T_STEPS * BATCH * NH * 2); // 64 MB

    // ---- prep ----
    // Wcomb = emb @ W0x (fold embedding into layer-0 input weights)
    sgemm_f32<<<dim3(GDIM / BN, VOCAB / BM), 256, 0, stream>>>(
        emb, w0, Wcomb, VOCAB, GDIM, EDIM);
    // pack layer-0 weights: [Wcomb | W0h] per lin-col
    pack_w<<<dim3(GDIM / 32, VOCAB / 32), dim3(32, 8), 0, stream>>>(
        Wcomb, Wpack0, 0, KP0);
    pack_w<<<dim3(GDIM / 32, NH / 32), dim3(32, 8), 0, stream>>>(
        w0 + (size_t)EDIM * GDIM, Wpack0, VOCAB, KP0);
    // pack layer-1 weights: [W1x | W1h] per lin-col
    pack_w<<<dim3(GDIM / 32, NH / 32), dim3(32, 8), 0, stream>>>(
        w1, Wpack1, 0, KP1);
    pack_w<<<dim3(GDIM / 32, NH / 32), dim3(32, 8), 0, stream>>>(
        w1 + (size_t)NH * GDIM, Wpack1, NH, KP1);
    // out_w -> bf16 n-major
    transpose_to_bf16<<<dim3(VOCAB / 32, NH / 32), dim3(32, 8), 0, stream>>>(
        outw, outwt, NH, VOCAB);
    // inputs -> bf16
    {
        size_t n4 = (size_t)T_STEPS * BATCH * VOCAB / 4;
        convert_to_bf16<<<(int)((n4 + 255) / 256), 256, 0, stream>>>(inputs, inbf, n4);
    }

    // ---- recurrence: 257 diagonal dispatches ----
    for (int d = 0; d <= T_STEPS; ++d) {
        __hip_bfloat16* hcur = (d & 1) ? h0pp1 : h0pp0;
        __hip_bfloat16* hprev = (d & 1) ? h0pp0 : h0pp1;
        lstm_diag<<<256, 512, 0, stream>>>(
            inbf, Wpack0, Wpack1, b0, b1, hcur, hprev, c0, c1, H1all, d);
    }

    // ---- logits = H1 @ out_w + out_b ----
    gemm_bt<<<dim3(VOCAB / 128, (T_STEPS * BATCH) / 128), 256, 0, stream>>>(
        H1all, outwt, outb, out, T_STEPS * BATCH, VOCAB, NH);
}

// Round 5
// 6087.700 us; speedup vs baseline: 6.8521x; 1.2483x over previous
//
#include <hip/hip_runtime.h>
#include <hip/hip_bf16.h>
#include <cstdint>
#include <cstddef>

#define T_STEPS 256
#define BATCH   128
#define VOCAB   256
#define EDIM    512
#define NH      1024
#define GDIM    4096   // 4*NH
#define NST0    40     // layer0 k-steps: 8 (x) + 32 (h)
#define NST1    64     // layer1 k-steps: 32 (h0) + 32 (h1)

typedef __attribute__((ext_vector_type(8))) short short8;
typedef __attribute__((ext_vector_type(4))) float floatx4;

__device__ __forceinline__ float sigmoidf_(float x) { return 1.0f / (1.0f + __expf(-x)); }
__device__ __forceinline__ float tanhf_(float x)    { return 1.0f - 2.0f / (__expf(2.0f * x) + 1.0f); }

typedef __attribute__((address_space(1))) const unsigned int guint;
typedef __attribute__((address_space(3))) unsigned int luint;
__device__ __forceinline__ void load_lds16(const void* g, void* l) {
    // async global->LDS, 16B/lane; LDS dest = wave-uniform base + lane*16
    __builtin_amdgcn_global_load_lds((guint*)g, (luint*)l, 16, 0, 0);
}

// ---------------- fp32 GEMM (prep only: Wcomb = emb @ W0x) ----------------
#define BM 128
#define BN 128
#define BK 16
__global__ __launch_bounds__(256) void sgemm_f32(
    const float* __restrict__ A, const float* __restrict__ B,
    float* __restrict__ C, int M, int N, int K)
{
    __shared__ float As[BK][BM + 4];
    __shared__ float Bs[BK][BN + 4];
    const int tid = threadIdx.x;
    const int tr = tid >> 4, tc = tid & 15;
    const int bm = blockIdx.y, bn = blockIdx.x;
    const float* Ab = A + (size_t)bm * BM * K;
    float acc[8][8];
    #pragma unroll
    for (int i = 0; i < 8; ++i)
        #pragma unroll
        for (int j = 0; j < 8; ++j) acc[i][j] = 0.f;
    for (int k0 = 0; k0 < K; k0 += BK) {
        #pragma unroll
        for (int l = 0; l < 2; ++l) {
            int idx = tid + l * 256;
            int row = idx >> 2, c4 = idx & 3;
            float4 v = *(const float4*)(Ab + (size_t)row * K + k0 + c4 * 4);
            As[c4 * 4 + 0][row] = v.x; As[c4 * 4 + 1][row] = v.y;
            As[c4 * 4 + 2][row] = v.z; As[c4 * 4 + 3][row] = v.w;
        }
        #pragma unroll
        for (int l = 0; l < 2; ++l) {
            int idx = tid + l * 256;
            int row = idx >> 5, c4 = idx & 31;
            *(float4*)&Bs[row][c4 * 4] = *(const float4*)(B + (size_t)(k0 + row) * N + bn * BN + c4 * 4);
        }
        __syncthreads();
        #pragma unroll
        for (int kk = 0; kk < BK; ++kk) {
            float4 a0 = *(const float4*)&As[kk][tr * 8];
            float4 a1 = *(const float4*)&As[kk][tr * 8 + 4];
            float4 b0 = *(const float4*)&Bs[kk][tc * 8];
            float4 b1 = *(const float4*)&Bs[kk][tc * 8 + 4];
            float av[8] = {a0.x, a0.y, a0.z, a0.w, a1.x, a1.y, a1.z, a1.w};
            float bv[8] = {b0.x, b0.y, b0.z, b0.w, b1.x, b1.y, b1.z, b1.w};
            #pragma unroll
            for (int i = 0; i < 8; ++i)
                #pragma unroll
                for (int j = 0; j < 8; ++j) acc[i][j] += av[i] * bv[j];
        }
        __syncthreads();
    }
    #pragma unroll
    for (int i = 0; i < 8; ++i) {
        size_t row = (size_t)bm * BM + tr * 8 + i;
        #pragma unroll
        for (int j = 0; j < 8; j += 4) {
            int col = bn * BN + tc * 8 + j;
            *(float4*)(C + row * N + col) =
                make_float4(acc[i][j], acc[i][j+1], acc[i][j+2], acc[i][j+3]);
        }
    }
}

// ---------------- transpose + fp32->bf16: dst[C][R] <- src[R][C] ----------------
__global__ __launch_bounds__(256) void transpose_to_bf16(
    const float* __restrict__ src, __hip_bfloat16* __restrict__ dst, int R, int C)
{
    __shared__ float t[32][33];
    int x = blockIdx.x * 32 + threadIdx.x;
    #pragma unroll
    for (int i = 0; i < 4; ++i) {
        int y = blockIdx.y * 32 + threadIdx.y + i * 8;
        t[threadIdx.y + i * 8][threadIdx.x] = src[(size_t)y * C + x];
    }
    __syncthreads();
    int x2 = blockIdx.y * 32 + threadIdx.x;
    #pragma unroll
    for (int i = 0; i < 4; ++i) {
        int y2 = blockIdx.x * 32 + threadIdx.y + i * 8;
        dst[(size_t)y2 * R + x2] = __float2bfloat16(t[threadIdx.x][threadIdx.y + i * 8]);
    }
}

// ------- pack weights into per-(block,k-step,n-tile) 1KB fragment blocks -------
// src fp32 [Ksrc][4096] (row k, col lincol = g*1024 + n). For block j (8 hid cols),
// n-tile t (0:[f|i], 1:[o|g]), k-step s (32 k): contiguous 1KB ordered [quad][l16][8],
// so a contiguous LDS copy IS the MFMA B-fragment layout (lane reads at lane*16B).
// elem_off = ((((j*NSTEPS + s)*2 + t)*64 + quad*16 + l16)*8 + jj
__global__ __launch_bounds__(256) void pack_w2(
    const float* __restrict__ src, __hip_bfloat16* __restrict__ dst,
    int koff, int NSTEPS)
{
    __shared__ float t[64][33];
    const int tid = threadIdx.x;
    const int xt = blockIdx.x;   // lincol tile of 64
    const int kt = blockIdx.y;   // k tile of 32
    {   // load 32k x 64lincol tile, coalesced, store transposed
        int yl = tid >> 3;                 // 0..31 k-local
        int x0 = (tid & 7) * 8;            // 0..56 lincol-local
        const float* p = src + (size_t)(kt * 32 + yl) * GDIM + xt * 64 + x0;
        float4 v0 = *(const float4*)p;
        float4 v1 = *(const float4*)(p + 4);
        t[x0 + 0][yl] = v0.x; t[x0 + 1][yl] = v0.y; t[x0 + 2][yl] = v0.z; t[x0 + 3][yl] = v0.w;
        t[x0 + 4][yl] = v1.x; t[x0 + 5][yl] = v1.y; t[x0 + 6][yl] = v1.z; t[x0 + 7][yl] = v1.w;
    }
    __syncthreads();
    {   // write: thread = (lincol_local, quad) -> 16B of 8 k-consecutive bf16
        int ll = tid >> 2;                 // 0..63
        int quad = tid & 3;
        int lincol = xt * 64 + ll;
        int g = lincol >> 10, n = lincol & 1023;
        int j = n >> 3, c = n & 7;
        int tt = g >> 1;
        int l16 = (g & 1) * 8 + c;
        int s = (koff >> 5) + kt;
        __hip_bfloat16 o[8];
        #pragma unroll
        for (int jj = 0; jj < 8; ++jj)
            o[jj] = __float2bfloat16(t[ll][quad * 8 + jj]);
        size_t off = ((((size_t)j * NSTEPS + s) * 2 + tt) * 64 + (size_t)quad * 16 + l16) * 8;
        *(uint4*)(dst + off) = *(const uint4*)o;
    }
}

// ---------------- fp32 -> bf16 convert ----------------
__global__ __launch_bounds__(256) void convert_to_bf16(
    const float* __restrict__ src, __hip_bfloat16* __restrict__ dst, size_t n4)
{
    size_t i = (size_t)blockIdx.x * 256 + threadIdx.x;
    if (i < n4) {
        float4 v = *(const float4*)(src + i * 4);
        __hip_bfloat16 o[4] = {__float2bfloat16(v.x), __float2bfloat16(v.y),
                               __float2bfloat16(v.z), __float2bfloat16(v.w)};
        *(uint2*)(dst + i * 4) = *(uint2*)o;
    }
}

// ---------------- bf16 MFMA GEMM: C[M][N] f32 = A[M][K] @ Bt[N][K] (+bias) ------
#define GKP 40
__global__ __launch_bounds__(256) void gemm_bt(
    const __hip_bfloat16* __restrict__ A, const __hip_bfloat16* __restrict__ Bt,
    const float* __restrict__ bias, float* __restrict__ C, int M, int N, int K)
{
    __shared__ __hip_bfloat16 As[128 * GKP];
    __shared__ __hip_bfloat16 Bs[128 * GKP];
    const int tid = threadIdx.x;
    const int wave = tid >> 6, lane = tid & 63;
    const int quad = lane >> 4, l16 = lane & 15;
    const int wm = (wave >> 1) * 64, wn = (wave & 1) * 64;
    const size_t Arow0 = (size_t)blockIdx.y * 128;
    const size_t Brow0 = (size_t)blockIdx.x * 128;
    floatx4 acc[4][4];
    #pragma unroll
    for (int i = 0; i < 4; ++i)
        #pragma unroll
        for (int j = 0; j < 4; ++j) acc[i][j] = (floatx4)0.f;

    for (int k0 = 0; k0 < K; k0 += 32) {
        #pragma unroll
        for (int l = 0; l < 2; ++l) {
            int idx = tid + l * 256;
            int row = idx >> 2, seg = idx & 3;
            *(uint4*)(As + row * GKP + seg * 8) =
                *(const uint4*)(A + (Arow0 + row) * K + k0 + seg * 8);
            *(uint4*)(Bs + row * GKP + seg * 8) =
                *(const uint4*)(Bt + (Brow0 + row) * K + k0 + seg * 8);
        }
        __syncthreads();
        short8 af[4], bf[4];
        #pragma unroll
        for (int i = 0; i < 4; ++i)
            af[i] = *(const short8*)(As + (wm + i * 16 + l16) * GKP + quad * 8);
        #pragma unroll
        for (int j = 0; j < 4; ++j)
            bf[j] = *(const short8*)(Bs + (wn + j * 16 + l16) * GKP + quad * 8);
        #pragma unroll
        for (int i = 0; i < 4; ++i)
            #pragma unroll
            for (int j = 0; j < 4; ++j)
                acc[i][j] = __builtin_amdgcn_mfma_f32_16x16x32_bf16(af[i], bf[j], acc[i][j], 0, 0, 0);
        __syncthreads();
    }
    #pragma unroll
    for (int i = 0; i < 4; ++i)
        #pragma unroll
        for (int j = 0; j < 4; ++j) {
            int col = (int)Brow0 + wn + j * 16 + l16;
            float bv = bias ? bias[col] : 0.f;
            #pragma unroll
            for (int r = 0; r < 4; ++r) {
                size_t row = Arow0 + wm + i * 16 + quad * 4 + r;
                C[row * N + col] = acc[i][j][r] + bv;
            }
        }
}

// ---------------- diagonal fused LSTM step, v2 ----------------
// 256 blocks: even=layer0 (h0[d]), odd=layer1 (h1[d-1]). Block owns 8 hid cols
// (2 n-tiles [f|i],[o|g]); 512 threads = 8 waves, wave w owns batch rows
// [16w,16w+16). A-fragments: per-lane 16B direct global loads (no LDS, no
// barrier). B: 16KB chunks (8 k-steps) staged via contiguous global_load_lds,
// double-buffered; barrier only once per 8 k-steps.
__global__ __launch_bounds__(512) void lstm_diag(
    const __hip_bfloat16* __restrict__ inbf,   // [256][128][256]
    const __hip_bfloat16* __restrict__ Wpack0, // [128][40][2][1KB]
    const __hip_bfloat16* __restrict__ Wpack1, // [128][64][2][1KB]
    const float* __restrict__ b0, const float* __restrict__ b1,
    __hip_bfloat16* __restrict__ h0_cur,
    const __hip_bfloat16* __restrict__ h0_prev,
    float* __restrict__ c0, float* __restrict__ c1,
    __hip_bfloat16* __restrict__ H1all,        // [256][128][1024]
    int d)
{
    const int layer = blockIdx.x & 1;
    const int j = blockIdx.x >> 1;
    if (layer == 0 && d >= T_STEPS) return;
    if (layer == 1 && d == 0) return;

    __shared__ __attribute__((aligned(16))) __hip_bfloat16 Bbuf[2][8192]; // 2 x 16KB

    const int tid = threadIdx.x;
    const int wave = tid >> 6, lane = tid & 63;
    const int quad = lane >> 4, l16 = lane & 15;

    const __hip_bfloat16 *Wp, *A0, *A1;
    int A0stride, NC, NCA0;
    const float* bb; float* cst; __hip_bfloat16* hout;
    bool first;
    if (layer == 0) {
        first = (d == 0);
        NC = first ? 1 : 5; NCA0 = 1;
        Wp = Wpack0 + (size_t)j * (NST0 * 1024);
        bb = b0; cst = c0;
        A0 = inbf + (size_t)d * (BATCH * VOCAB); A0stride = VOCAB;
        A1 = h0_prev;
        hout = h0_cur;
    } else {
        first = (d == 1);
        NC = first ? 4 : 8; NCA0 = 4;
        Wp = Wpack1 + (size_t)j * (NST1 * 1024);
        bb = b1; cst = c1;
        A0 = h0_prev; A0stride = NH;
        A1 = (d >= 2) ? (H1all + (size_t)(d - 2) * (BATCH * NH)) : h0_prev; // dummy if d==1
        hout = H1all + (size_t)(d - 1) * (BATCH * NH);
    }
    const int row = wave * 16 + l16;
    const __hip_bfloat16* pA0 = A0 + (size_t)row * A0stride + quad * 8;
    const __hip_bfloat16* pA1 = A1 + (size_t)row * NH + quad * 8;

    #define STAGE(c, b) do { \
        const __hip_bfloat16* g0_ = Wp + (size_t)(c) * 8192 + wave * 512 + lane * 8; \
        load_lds16(g0_, &Bbuf[b][wave * 512]); \
        load_lds16(g0_ + 8 * 512, &Bbuf[b][(wave + 8) * 512]); \
    } while (0)

    const int cc = j * 8 + (l16 & 7);
    float bv0 = bb[((l16 < 8) ? 0 : 1) * NH + cc];
    float bv1 = bb[((l16 < 8) ? 2 : 3) * NH + cc];
    floatx4 acc0 = {bv0, bv0, bv0, bv0};
    floatx4 acc1 = {bv1, bv1, bv1, bv1};

    STAGE(0, 0);
    __syncthreads();
    for (int c = 0; c < NC; ++c) {
        const int cur = c & 1, nxt = cur ^ 1;
        if (c + 1 < NC) STAGE(c + 1, nxt);
        const __hip_bfloat16* pa = (c < NCA0) ? (pA0 + (size_t)c * 8 * 32)
                                              : (pA1 + (size_t)(c - NCA0) * 8 * 32);
        short8 af[8];
        #pragma unroll
        for (int ss = 0; ss < 8; ++ss)
            af[ss] = *(const short8*)(pa + ss * 32);
        #pragma unroll
        for (int ss = 0; ss < 8; ++ss) {
            short8 bf0 = *(const short8*)&Bbuf[cur][(ss * 2 + 0) * 512 + lane * 8];
            short8 bf1 = *(const short8*)&Bbuf[cur][(ss * 2 + 1) * 512 + lane * 8];
            acc0 = __builtin_amdgcn_mfma_f32_16x16x32_bf16(af[ss], bf0, acc0, 0, 0, 0);
            acc1 = __builtin_amdgcn_mfma_f32_16x16x32_bf16(af[ss], bf1, acc1, 0, 0, 0);
        }
        __syncthreads();
    }
    #undef STAGE

    // epilogue: lanes l16<8 hold (f,o), lanes l16>=8 hold (i,g) for col cc
    #pragma unroll
    for (int r = 0; r < 4; ++r) {
        float a0 = acc0[r], a1 = acc1[r];
        float p0 = __shfl_xor(a0, 8, 64);
        float p1 = __shfl_xor(a1, 8, 64);
        if (l16 < 8) {
            int b = 16 * wave + quad * 4 + r;
            float f  = sigmoidf_(a0);
            float ig = sigmoidf_(p0);
            float oo = sigmoidf_(a1);
            float gg = tanhf_(p1);
            size_t idx = (size_t)b * NH + cc;
            float cold = first ? 0.f : cst[idx];
            float cn = f * cold + ig * gg;
            float hn = oo * tanhf_(cn);
            cst[idx] = cn;
            hout[idx] = __float2bfloat16(hn);
        }
    }
}

extern "C" void kernel_launch(void* const* d_in, const int* in_sizes, int n_in,
                              void* d_out, int out_size, void* d_ws, size_t ws_size,
                              hipStream_t stream)
{
    const float* inputs = (const float*)d_in[0];  // [256,128,256]
    const float* emb    = (const float*)d_in[1];  // [256,512]
    const float* w0     = (const float*)d_in[2];  // [1536,4096]
    const float* b0     = (const float*)d_in[3];  // [4096]
    const float* w1     = (const float*)d_in[4];  // [2048,4096]
    const float* b1     = (const float*)d_in[5];  // [4096]
    const float* outw   = (const float*)d_in[6];  // [1024,256]
    const float* outb   = (const float*)d_in[7];  // [256]
    float* out = (float*)d_out;                   // [32768,256]

    char* ws = (char*)d_ws;
    size_t off = 0;
    auto take = [&](size_t bytes) { char* p = ws + off; off += (bytes + 255) & ~(size_t)255; return p; };
    float* Wcomb = (float*)take((size_t)VOCAB * GDIM * 4);                          // 4 MB
    __hip_bfloat16* Wpack0 = (__hip_bfloat16*)take((size_t)128 * NST0 * 1024 * 2);  // 10 MB
    __hip_bfloat16* Wpack1 = (__hip_bfloat16*)take((size_t)128 * NST1 * 1024 * 2);  // 16 MB
    __hip_bfloat16* outwt  = (__hip_bfloat16*)take((size_t)NH * VOCAB * 2);         // 0.5 MB
    __hip_bfloat16* inbf   = (__hip_bfloat16*)take((size_t)T_STEPS * BATCH * VOCAB * 2); // 16 MB
    __hip_bfloat16* h0pp0  = (__hip_bfloat16*)take((size_t)BATCH * NH * 2);
    __hip_bfloat16* h0pp1  = (__hip_bfloat16*)take((size_t)BATCH * NH * 2);
    float* c0 = (float*)take((size_t)BATCH * NH * 4);
    float* c1 = (float*)take((size_t)BATCH * NH * 4);
    __hip_bfloat16* H1all  = (__hip_bfloat16*)take((size_t)T_STEPS * BATCH * NH * 2); // 64 MB

    // ---- prep ----
    sgemm_f32<<<dim3(GDIM / BN, VOCAB / BM), 256, 0, stream>>>(
        emb, w0, Wcomb, VOCAB, GDIM, EDIM);
    // layer-0: [Wcomb (k 0..255) | W0h (k 256..1279)]
    pack_w2<<<dim3(64, VOCAB / 32), 256, 0, stream>>>(Wcomb, Wpack0, 0, NST0);
    pack_w2<<<dim3(64, NH / 32), 256, 0, stream>>>(w0 + (size_t)EDIM * GDIM, Wpack0, VOCAB, NST0);
    // layer-1: [W1x (k 0..1023) | W1h (k 1024..2047)]
    pack_w2<<<dim3(64, NH / 32), 256, 0, stream>>>(w1, Wpack1, 0, NST1);
    pack_w2<<<dim3(64, NH / 32), 256, 0, stream>>>(w1 + (size_t)NH * GDIM, Wpack1, NH, NST1);
    // out_w -> bf16 n-major
    transpose_to_bf16<<<dim3(VOCAB / 32, NH / 32), dim3(32, 8), 0, stream>>>(
        outw, outwt, NH, VOCAB);
    // inputs -> bf16
    {
        size_t n4 = (size_t)T_STEPS * BATCH * VOCAB / 4;
        convert_to_bf16<<<(int)((n4 + 255) / 256), 256, 0, stream>>>(inputs, inbf, n4);
    }

    // ---- recurrence: 257 diagonal dispatches ----
    for (int d = 0; d <= T_STEPS; ++d) {
        __hip_bfloat16* hcur = (d & 1) ? h0pp1 : h0pp0;
        __hip_bfloat16* hprev = (d & 1) ? h0pp0 : h0pp1;
        lstm_diag<<<256, 512, 0, stream>>>(
            inbf, Wpack0, Wpack1, b0, b1, hcur, hprev, c0, c1, H1all, d);
    }

    // ---- logits = H1 @ out_w + out_b ----
    gemm_bt<<<dim3(VOCAB / 128, (T_STEPS * BATCH) / 128), 256, 0, stream>>>(
        H1all, outwt, outb, out, T_STEPS * BATCH, VOCAB, NH);
}